// Round 16
// baseline (188.106 us; speedup 1.0000x reference)
//
#include <hip/hip_runtime.h>
#include <hip/hip_bf16.h>

// RelativeAttention B=2,N=1024,C=512,H=8,HD=64 — round 15: 3-barrier attn.
//  wprep/proj_mfma/out_mfma = round-14 VERBATIM (185.1us total).
//  attn changes: khs/vts double-buffered (khs XOR-swizzled unpadded, vts
//  unpadded) -> bar4 removed (3 barriers/iter); X1 hoisted before bar3
//  (reads only wave-own P slab -> in-wave lgkm ordering suffices); q1
//  aliases khs2[0] (prologue-only) to fit LDS = 160256B.
// ws: qh 2MB | kh 2MB | vhT 2MB | xpart 8MB | lsum 128KB | WT 2.5MB

typedef __attribute__((ext_vector_type(8))) short short8;
typedef __attribute__((ext_vector_type(4))) short short4v;
typedef __attribute__((ext_vector_type(4))) float f32x4;

#if defined(__has_builtin)
#  if __has_builtin(__builtin_amdgcn_mfma_f32_16x16x16bf16_1k)
#    define HAVE_MFMA16 1
#  endif
#endif
#ifndef HAVE_MFMA16
#  define HAVE_MFMA16 0
#endif

__device__ __forceinline__ unsigned short f2b(float f) {
    union { float f; unsigned u; } v; v.f = f;
    unsigned r = (v.u + 0x7FFF + ((v.u >> 16) & 1)) >> 16;   // RNE
    return (unsigned short)r;
}
__device__ __forceinline__ float b2f(unsigned short h) {
    union { unsigned u; float f; } v; v.u = ((unsigned)h) << 16;
    return v.f;
}

__device__ __forceinline__ unsigned cvt_pk(float a, float b) {
    unsigned r;
    asm("v_cvt_pk_bf16_f32 %0, %1, %2" : "=v"(r) : "v"(a), "v"(b));
    return r;
}

// lgkm-drain + raw barrier: LDS ordered; global loads NOT drained.
#define LGKM0_BAR()                                            \
    do {                                                       \
        asm volatile("s_waitcnt lgkmcnt(0)" ::: "memory");     \
        __builtin_amdgcn_s_barrier();                          \
        asm volatile("" ::: "memory");                         \
    } while (0)

// ---------------------------------------------------------------------------
// wprep: W f32 [k][n] -> WT bf16 [n][k]. z=0..2: Wq/Wk/Wv. z=3: Wp -> hi+lo.
// ---------------------------------------------------------------------------
__global__ __launch_bounds__(256) void wprep(
    const float* __restrict__ W0, const float* __restrict__ W1,
    const float* __restrict__ W2, const float* __restrict__ W3,
    unsigned short* __restrict__ WT)
{
    const int z = blockIdx.z;
    const float* W = (z == 0) ? W0 : ((z == 1) ? W1 : ((z == 2) ? W2 : W3));
    __shared__ float Ts[64][65];
    const int t = threadIdx.x;
    const int k0 = blockIdx.x * 64, n0 = blockIdx.y * 64;
    const int kr = t >> 2, nc = (t & 3) * 16;
    #pragma unroll
    for (int q = 0; q < 4; ++q) {
        float4 v = *reinterpret_cast<const float4*>(
            W + (size_t)(k0 + kr) * 512 + n0 + nc + q * 4);
        Ts[kr][nc + q * 4 + 0] = v.x; Ts[kr][nc + q * 4 + 1] = v.y;
        Ts[kr][nc + q * 4 + 2] = v.z; Ts[kr][nc + q * 4 + 3] = v.w;
    }
    __syncthreads();
    const int nl = t >> 2, kc = (t & 3) * 16;
    if (z < 3) {
        unsigned short* T = WT + (size_t)z * 262144;
        unsigned short tmp[16];
        #pragma unroll
        for (int e = 0; e < 16; ++e) tmp[e] = f2b(Ts[kc + e][nl]);
        unsigned short* dst = T + (size_t)(n0 + nl) * 512 + k0 + kc;
        *reinterpret_cast<short8*>(dst)     = *reinterpret_cast<short8*>(&tmp[0]);
        *reinterpret_cast<short8*>(dst + 8) = *reinterpret_cast<short8*>(&tmp[8]);
    } else {
        unsigned short* Th = WT + (size_t)3 * 262144;
        unsigned short* Tl = WT + (size_t)4 * 262144;
        unsigned short hi[16], lo[16];
        #pragma unroll
        for (int e = 0; e < 16; ++e) {
            float v = Ts[kc + e][nl];
            hi[e] = f2b(v);
            lo[e] = f2b(v - b2f(hi[e]));
        }
        unsigned short* dh = Th + (size_t)(n0 + nl) * 512 + k0 + kc;
        unsigned short* dl = Tl + (size_t)(n0 + nl) * 512 + k0 + kc;
        *reinterpret_cast<short8*>(dh)     = *reinterpret_cast<short8*>(&hi[0]);
        *reinterpret_cast<short8*>(dh + 8) = *reinterpret_cast<short8*>(&hi[8]);
        *reinterpret_cast<short8*>(dl)     = *reinterpret_cast<short8*>(&lo[0]);
        *reinterpret_cast<short8*>(dl + 8) = *reinterpret_cast<short8*>(&lo[8]);
    }
}

// ---------------------------------------------------------------------------
// proj_mfma: round-13 VERBATIM. grid (32,8,3), 256 thr.
// ---------------------------------------------------------------------------
__global__ __launch_bounds__(256) void proj_mfma(
    const float* __restrict__ qg, const float* __restrict__ kg,
    const float* __restrict__ vg, const unsigned short* __restrict__ WT,
    unsigned short* __restrict__ qhb, unsigned short* __restrict__ khb,
    unsigned short* __restrict__ vtb)
{
    const int z = blockIdx.z;
    const float* X = (z == 0) ? qg : ((z == 1) ? kg : vg);
    const unsigned short* WTz = WT + (size_t)z * 262144;
    const float scale = (z == 0) ? 0.125f : 1.0f;

    __shared__ unsigned short As[64][72];
    const int t = threadIdx.x, w = t >> 6, l = t & 63;
    const int l16 = l & 15, lg = l >> 4;
    const int m0 = blockIdx.x * 64, n0 = blockIdx.y * 64;
    const int ra = t >> 2, kc = (t & 3) * 16;

    f32x4 acc[4];
    #pragma unroll
    for (int cs = 0; cs < 4; ++cs) acc[cs] = 0.0f;

    for (int k0 = 0; k0 < 512; k0 += 64) {
        float4 va[4];
        #pragma unroll
        for (int qq = 0; qq < 4; ++qq)
            va[qq] = *reinterpret_cast<const float4*>(
                X + (size_t)(m0 + ra) * 512 + k0 + kc + qq * 4);
        uint4 pk0, pk1;
        pk0.x = cvt_pk(va[0].x, va[0].y); pk0.y = cvt_pk(va[0].z, va[0].w);
        pk0.z = cvt_pk(va[1].x, va[1].y); pk0.w = cvt_pk(va[1].z, va[1].w);
        pk1.x = cvt_pk(va[2].x, va[2].y); pk1.y = cvt_pk(va[2].z, va[2].w);
        pk1.z = cvt_pk(va[3].x, va[3].y); pk1.w = cvt_pk(va[3].z, va[3].w);
        __syncthreads();
        *reinterpret_cast<uint4*>(&As[ra][kc])     = pk0;
        *reinterpret_cast<uint4*>(&As[ra][kc + 8]) = pk1;
        __syncthreads();
        #pragma unroll
        for (int kk = 0; kk < 2; ++kk) {
            short8 a = *reinterpret_cast<const short8*>(
                &As[w * 16 + l16][kk * 32 + 8 * lg]);
            #pragma unroll
            for (int cs = 0; cs < 4; ++cs) {
                short8 b = *reinterpret_cast<const short8*>(
                    WTz + (size_t)(n0 + cs * 16 + l16) * 512 + k0 + kk * 32 + 8 * lg);
                acc[cs] = __builtin_amdgcn_mfma_f32_16x16x32_bf16(a, b, acc[cs], 0, 0, 0);
            }
        }
    }

    const int h = blockIdx.y;
    if (z < 2) {
        unsigned short* Y = (z == 0) ? qhb : khb;
        #pragma unroll
        for (int cs = 0; cs < 4; ++cs)
            #pragma unroll
            for (int r = 0; r < 4; ++r) {
                int m = m0 + w * 16 + lg * 4 + r;
                int bb = m >> 10, nn = m & 1023;
                Y[(((size_t)((bb * 8 + h) * 1024 + nn)) << 6) + cs * 16 + l16] =
                    f2b(acc[cs][r] * scale);
            }
    } else {
        int mbase = m0 + w * 16 + lg * 4;
        int bb = mbase >> 10, nn = mbase & 1023;
        #pragma unroll
        for (int cs = 0; cs < 4; ++cs) {
            ushort4 o;
            o.x = f2b(acc[cs][0]); o.y = f2b(acc[cs][1]);
            o.z = f2b(acc[cs][2]); o.w = f2b(acc[cs][3]);
            *reinterpret_cast<ushort4*>(
                vtb + (((size_t)(bb * 8 + h) * 64 + cs * 16 + l16) << 10) + nn) = o;
        }
    }
}

// ---------------------------------------------------------------------------
// out_mfma: round-14 VERBATIM. grid (32, 8), 256 thr.
// ---------------------------------------------------------------------------
__global__ __launch_bounds__(256) void out_mfma(
    const float* __restrict__ xpart, const float* __restrict__ lsump,
    const unsigned short* __restrict__ WT, const float* __restrict__ bp,
    float* __restrict__ out)
{
    const unsigned short* WPhi = WT + (size_t)3 * 262144;
    const unsigned short* WPlo = WT + (size_t)4 * 262144;
    __shared__ unsigned short Ah[64][72];
    __shared__ unsigned short Al[64][72];
    const int t = threadIdx.x, w = t >> 6, l = t & 63;
    const int l16 = l & 15, lg = l >> 4;
    const int m0 = blockIdx.x * 64, n0 = blockIdx.y * 64;
    const int ra = t >> 2, kc = (t & 3) * 16;
    const int mrow = m0 + ra, bb = mrow >> 10, nn = mrow & 1023;

    f32x4 acc[4];
    #pragma unroll
    for (int cs = 0; cs < 4; ++cs) acc[cs] = 0.0f;

    for (int k0 = 0; k0 < 512; k0 += 64) {
        const int h = k0 >> 6;
        float ls = lsump[(bb * 8 + h) * 1024 + nn]
                 + lsump[16384 + (bb * 8 + h) * 1024 + nn];
        float inv = 1.0f / ls;
        unsigned short hi[16], lo[16];
        #pragma unroll
        for (int qq = 0; qq < 4; ++qq) {
            size_t base = ((size_t)(bb * 1024 + nn)) * 512 + k0 + kc + qq * 4;
            float4 v0 = *reinterpret_cast<const float4*>(xpart + base);
            float4 v1 = *reinterpret_cast<const float4*>(xpart + (1u << 20) + base);
            float e0 = (v0.x + v1.x) * inv, e1 = (v0.y + v1.y) * inv;
            float e2 = (v0.z + v1.z) * inv, e3 = (v0.w + v1.w) * inv;
            hi[qq * 4 + 0] = f2b(e0); lo[qq * 4 + 0] = f2b(e0 - b2f(hi[qq * 4 + 0]));
            hi[qq * 4 + 1] = f2b(e1); lo[qq * 4 + 1] = f2b(e1 - b2f(hi[qq * 4 + 1]));
            hi[qq * 4 + 2] = f2b(e2); lo[qq * 4 + 2] = f2b(e2 - b2f(hi[qq * 4 + 2]));
            hi[qq * 4 + 3] = f2b(e3); lo[qq * 4 + 3] = f2b(e3 - b2f(hi[qq * 4 + 3]));
        }
        __syncthreads();
        *reinterpret_cast<short8*>(&Ah[ra][kc])     = *reinterpret_cast<short8*>(&hi[0]);
        *reinterpret_cast<short8*>(&Ah[ra][kc + 8]) = *reinterpret_cast<short8*>(&hi[8]);
        *reinterpret_cast<short8*>(&Al[ra][kc])     = *reinterpret_cast<short8*>(&lo[0]);
        *reinterpret_cast<short8*>(&Al[ra][kc + 8]) = *reinterpret_cast<short8*>(&lo[8]);
        __syncthreads();
        #pragma unroll
        for (int kk = 0; kk < 2; ++kk) {
            short8 ah = *reinterpret_cast<const short8*>(
                &Ah[w * 16 + l16][kk * 32 + 8 * lg]);
            short8 al = *reinterpret_cast<const short8*>(
                &Al[w * 16 + l16][kk * 32 + 8 * lg]);
            #pragma unroll
            for (int cs = 0; cs < 4; ++cs) {
                size_t wb = (size_t)(n0 + cs * 16 + l16) * 512 + k0 + kk * 32 + 8 * lg;
                short8 bh = *reinterpret_cast<const short8*>(WPhi + wb);
                short8 bl = *reinterpret_cast<const short8*>(WPlo + wb);
                acc[cs] = __builtin_amdgcn_mfma_f32_16x16x32_bf16(ah, bh, acc[cs], 0, 0, 0);
                acc[cs] = __builtin_amdgcn_mfma_f32_16x16x32_bf16(ah, bl, acc[cs], 0, 0, 0);
                acc[cs] = __builtin_amdgcn_mfma_f32_16x16x32_bf16(al, bh, acc[cs], 0, 0, 0);
            }
        }
    }

    #pragma unroll
    for (int cs = 0; cs < 4; ++cs) {
        int col = n0 + cs * 16 + l16;
        float bv = bp[col];
        #pragma unroll
        for (int r = 0; r < 4; ++r) {
            int row = m0 + w * 16 + lg * 4 + r;
            out[(size_t)row * 512 + col] = acc[cs][r] + bv;
        }
    }
}

// ---------------------------------------------------------------------------
// attn: 3-barrier variant. grid 256 = b(2) x itile(64) x jsplit(2); 8 waves.
// ---------------------------------------------------------------------------
__global__ __launch_bounds__(512, 2) void attn_mfma(
    const unsigned short* __restrict__ qhg, const unsigned short* __restrict__ khg,
    const unsigned short* __restrict__ vtg, const float* __restrict__ rpb,
    const float* __restrict__ mask, float* __restrict__ xpart,
    float* __restrict__ lsump)
{
    __shared__ unsigned short rpb_s[2][16][16][72]; // dbuf rpb         73728B
    __shared__ unsigned short khs2[2][8][16][64];   // dbuf kh, XOR-swz 32768B
    __shared__ unsigned short vts2[2][8][64][16];   // dbuf vt          32768B
    __shared__ unsigned short P[8][16][40];         // j16..39 ZERO     10240B
    __shared__ float S2s[16][8][17];                //                   8704B
    __shared__ float mask_s[512];                   //                   2048B
                                                    // total           160256B
    const int bid = blockIdx.x;
    const int js = bid & 1, it = (bid >> 1) & 63, b = bid >> 7;
    const int i0 = it * 16, jb = js * 512;
    const int t = threadIdx.x, w = t >> 6, l = t & 63;
    const int lg = l >> 4, l16 = l & 15;

    const int sj = (t >> 3) & 15, sc = (t & 7) * 8, sib = t >> 7;
    const int kh_h = t >> 6, kh_j = (t >> 2) & 15, kh_c = (t & 3) * 16;
    const int vt_h = t >> 6, vt_c = t & 63;

    const float* rpbb = rpb + ((size_t)(b * 1024 + i0) << 16);

#define RPB_ISSUE(PF, J0)                                                      \
    _Pragma("unroll")                                                          \
    for (int itr = 0; itr < 4; ++itr) {                                        \
        const float4* s_ = reinterpret_cast<const float4*>(                    \
            rpbb + ((size_t)(sib + 4 * itr) << 16) +                           \
            (size_t)((J0) + sj) * 64 + sc);                                    \
        PF[2 * itr] = s_[0]; PF[2 * itr + 1] = s_[1];                          \
    }

#define RPB_WRITE(PF, BUF)                                                     \
    _Pragma("unroll")                                                          \
    for (int itr = 0; itr < 4; ++itr) {                                        \
        float4 ua = PF[2 * itr], ub = PF[2 * itr + 1];                         \
        uint4 pk;                                                              \
        pk.x = cvt_pk(ua.x, ua.y); pk.y = cvt_pk(ua.z, ua.w);                  \
        pk.z = cvt_pk(ub.x, ub.y); pk.w = cvt_pk(ub.z, ub.w);                  \
        *reinterpret_cast<uint4*>(&rpb_s[BUF][sib + 4 * itr][sj][sc]) = pk;    \
    }

#define KH_ISSUE(KP, J0)                                                       \
    {                                                                          \
        const unsigned short* p_ = khg + ((size_t)(b * 8 + kh_h) << 16) +      \
            (size_t)((J0) + kh_j) * 64 + kh_c;                                 \
        KP[0] = *reinterpret_cast<const short8*>(p_);                          \
        KP[1] = *reinterpret_cast<const short8*>(p_ + 8);                      \
    }

// XOR-swizzled write: chunk cc (8 elems) -> cc ^ (j&7). Read applies same XOR.
#define KH_WRITE(KP, BUF)                                                      \
    {                                                                          \
        int s_ = kh_j & 7, c0_ = kh_c >> 3;                                    \
        *reinterpret_cast<short8*>(&khs2[BUF][kh_h][kh_j][(c0_ ^ s_) * 8]) = KP[0]; \
        *reinterpret_cast<short8*>(&khs2[BUF][kh_h][kh_j][((c0_ + 1) ^ s_) * 8]) = KP[1]; \
    }

#define VT_ISSUE(VP, J0)                                                       \
    {                                                                          \
        const unsigned short* p_ = vtg + ((size_t)(b * 8 + vt_h) << 16) +      \
            ((size_t)vt_c << 10) + (J0);                                       \
        VP[0] = *reinterpret_cast<const short8*>(p_);                          \
        VP[1] = *reinterpret_cast<const short8*>(p_ + 8);                      \
    }

#define VT_WRITE(VP, BUF)                                                      \
    {                                                                          \
        *reinterpret_cast<short8*>(&vts2[BUF][vt_h][vt_c][0]) = VP[0];         \
        *reinterpret_cast<short8*>(&vts2[BUF][vt_h][vt_c][8]) = VP[1];         \
    }

    // ---- prologue: q tile into khs2[0] alias (prologue-only), mask, P ----
    unsigned short (*q1)[16][72] =
        reinterpret_cast<unsigned short (*)[16][72]>(&khs2[0][0][0][0]);
    {
        int h = t >> 6, i = (t >> 2) & 15, c = (t & 3) * 16;
        const short8* src = reinterpret_cast<const short8*>(
            qhg + (((size_t)(b * 8 + h) * 1024 + i0 + i) << 6) + c);
        *reinterpret_cast<short8*>(&q1[h][i][c])     = src[0];
        *reinterpret_cast<short8*>(&q1[h][i][c + 8]) = src[1];
    }
    if (t < 128) {
        *reinterpret_cast<float4*>(&mask_s[t * 4]) =
            *reinterpret_cast<const float4*>(&mask[b * 1024 + jb + t * 4]);
    }
    {
        unsigned short* P1 = &P[0][0][0];
        #pragma unroll
        for (int r = 0; r < 10; ++r) P1[t + 512 * r] = 0;   // 5120 = 512*10
    }
    float mrow[4];
    #pragma unroll
    for (int r = 0; r < 4; r++) mrow[r] = mask[b * 1024 + i0 + lg * 4 + r];

    float4 pfA[8], pfB[8];
    short8 kpfA[2], kpfB[2], vpfA[2], vpfB[2];
    RPB_ISSUE(pfA, jb)
    KH_ISSUE(kpfA, jb)
    VT_ISSUE(vpfA, jb)

    LGKM0_BAR();   // q1/mask_s/P visible; batch(0) in flight

    short8 a1[2];
    a1[0] = *reinterpret_cast<const short8*>(&q1[w][l16][8 * lg]);
    a1[1] = *reinterpret_cast<const short8*>(&q1[w][l16][32 + 8 * lg]);
    short8 bq[2][2];
    #pragma unroll
    for (int il = 0; il < 2; ++il) {
        bq[il][0] = *reinterpret_cast<const short8*>(
            &q1[l16 & 7][2 * w + il][8 * lg]);
        bq[il][1] = *reinterpret_cast<const short8*>(
            &q1[l16 & 7][2 * w + il][32 + 8 * lg]);
    }

    LGKM0_BAR();   // all q reads done -> khs2[0] (alias) may be overwritten

    const int jo = (lg < 2) ? 8 * lg : 0;   // K32-fallback zero-pad clamp
    const int ro = jo;
    (void)ro;

    f32x4 x1[4];
    #pragma unroll
    for (int cs = 0; cs < 4; cs++) x1[cs] = 0.0f;
    f32x4 x2[2][4];
    #pragma unroll
    for (int il = 0; il < 2; il++)
        #pragma unroll
        for (int cg = 0; cg < 4; cg++) x2[il][cg] = 0.0f;
    float lsum[4] = {0.f, 0.f, 0.f, 0.f};

#if HAVE_MFMA16
#define X1_BODY(CUR)                                                           \
    {                                                                          \
        short4v pa = *reinterpret_cast<const short4v*>(&P[w][l16][4 * lg]);    \
        _Pragma("unroll")                                                      \
        for (int cs = 0; cs < 4; ++cs) {                                       \
            short4v vb = *reinterpret_cast<const short4v*>(                    \
                &vts2[CUR][w][cs * 16 + l16][4 * lg]);                         \
            x1[cs] = __builtin_amdgcn_mfma_f32_16x16x16bf16_1k(pa, vb, x1[cs], 0, 0, 0); \
        }                                                                      \
    }
#define X2_BODY(CUR)                                                           \
    _Pragma("unroll")                                                          \
    for (int il = 0; il < 2; ++il) {                                           \
        int i = 2 * w + il;                                                    \
        short4v pa2 = *reinterpret_cast<const short4v*>(&P[l16 & 7][i][4 * lg]); \
        _Pragma("unroll")                                                      \
        for (int cg = 0; cg < 4; ++cg) {                                       \
            short4v bb;                                                        \
            _Pragma("unroll")                                                  \
            for (int e = 0; e < 4; ++e)                                        \
                bb[e] = (short)rpb_s[CUR][i][4 * lg + e][cg * 16 + l16];       \
            x2[il][cg] = __builtin_amdgcn_mfma_f32_16x16x16bf16_1k(pa2, bb, x2[il][cg], 0, 0, 0); \
        }                                                                      \
    }
#else
#define X1_BODY(CUR)                                                           \
    {                                                                          \
        short8 pa = *reinterpret_cast<const short8*>(&P[w][l16][8 * lg]);      \
        _Pragma("unroll")                                                      \
        for (int cs = 0; cs < 4; ++cs) {                                       \
            short8 vb = *reinterpret_cast<const short8*>(                      \
                &vts2[CUR][w][cs * 16 + l16][jo]);                             \
            x1[cs] = __builtin_amdgcn_mfma_f32_16x16x32_bf16(pa, vb, x1[cs], 0, 0, 0); \
        }                                                                      \
    }
#define X2_BODY(CUR)                                                           \
    _Pragma("unroll")                                                          \
    for (int il = 0; il < 2; ++il) {                                           \
        int i = 2 * w + il;                                                    \
        short8 pa2 = *reinterpret_cast<const short8*>(&P[l16 & 7][i][8 * lg]); \
        _Pragma("unroll")                                                      \
        for (int cg = 0; cg < 4; ++cg) {                                       \
            short8 bb;                                                         \
            _Pragma("unroll")                                                  \
            for (int e = 0; e < 8; ++e)                                        \
                bb[e] = (short)rpb_s[CUR][i][ro + e][cg * 16 + l16];           \
            x2[il][cg] = __builtin_amdgcn_mfma_f32_16x16x32_bf16(pa2, bb, x2[il][cg], 0, 0, 0); \
        }                                                                      \
    }
#endif

#define ATTN_ITER(T, PFC, KPC, VPC, PFN, KPN, VPN)                             \
    {                                                                          \
        const int jt = (T);                                                    \
        const int cur = jt & 1;                                                \
        const int j0 = jb + jt * 16;                                           \
        if (jt < 31) {                                                         \
            RPB_ISSUE(PFN, j0 + 16)                                            \
            KH_ISSUE(KPN, j0 + 16)                                             \
            VT_ISSUE(VPN, j0 + 16)                                             \
        }                                                                      \
        RPB_WRITE(PFC, cur)                                                    \
        KH_WRITE(KPC, cur)                                                     \
        VT_WRITE(VPC, cur)                                                     \
        LGKM0_BAR();  /* bar1: staged tiles visible */                         \
        f32x4 C1; C1 = 0.0f;                                                   \
        {                                                                      \
            short8 kb0 = *reinterpret_cast<const short8*>(                     \
                &khs2[cur][w][l16][(lg ^ (l16 & 7)) * 8]);                     \
            short8 kb1 = *reinterpret_cast<const short8*>(                     \
                &khs2[cur][w][l16][((4 + lg) ^ (l16 & 7)) * 8]);               \
            C1 = __builtin_amdgcn_mfma_f32_16x16x32_bf16(a1[0], kb0, C1, 0, 0, 0); \
            C1 = __builtin_amdgcn_mfma_f32_16x16x32_bf16(a1[1], kb1, C1, 0, 0, 0); \
        }                                                                      \
        _Pragma("unroll")                                                      \
        for (int il = 0; il < 2; ++il) {                                       \
            int i = 2 * w + il;                                                \
            f32x4 D2; D2 = 0.0f;                                               \
            _Pragma("unroll")                                                  \
            for (int ch = 0; ch < 2; ++ch) {                                   \
                short8 ar = *reinterpret_cast<const short8*>(                  \
                    &rpb_s[cur][i][l16][ch * 32 + 8 * lg]);                    \
                D2 = __builtin_amdgcn_mfma_f32_16x16x32_bf16(ar, bq[il][ch], D2, 0, 0, 0); \
            }                                                                  \
            if (l16 < 8) {                                                     \
                _Pragma("unroll")                                              \
                for (int r = 0; r < 4; ++r)                                    \
                    S2s[i][l16][4 * lg + r] = D2[r];                           \
            }                                                                  \
        }                                                                      \
        LGKM0_BAR();  /* bar2: S2s ready */                                    \
        {                                                                      \
            float mj = mask_s[jt * 16 + l16];                                  \
            _Pragma("unroll")                                                  \
            for (int r = 0; r < 4; ++r) {                                      \
                int ir = lg * 4 + r;                                           \
                float mi = mrow[r];                                            \
                float pm = (fmaxf(mi, mj) < 0.f) ? 0.f : fminf(mi, mj);        \
                float s = C1[r] + S2s[ir][w][l16] + pm;                        \
                float p = __expf(s);                                           \
                lsum[r] += p;                                                  \
                P[w][ir][l16] = f2b(p);                                        \
            }                                                                  \
        }                                                                      \
        X1_BODY(cur)  /* wave-own P slab + vts2: no barrier needed */          \
        LGKM0_BAR();  /* bar3: P ready for cross-wave X2 */                    \
        X2_BODY(cur)                                                           \
        /* no bar4: all tiles double-buffered; next write >=3 barriers away */ \
    }

    for (int th = 0; th < 16; ++th) {
        ATTN_ITER(2 * th,     pfA, kpfA, vpfA, pfB, kpfB, vpfB)
        ATTN_ITER(2 * th + 1, pfB, kpfB, vpfB, pfA, kpfA, vpfA)
    }

    // ---- epilogue ----
    #pragma unroll
    for (int r = 0; r < 4; ++r) {
        float v = lsum[r];
        v += __shfl_xor(v, 1, 64); v += __shfl_xor(v, 2, 64);
        v += __shfl_xor(v, 4, 64); v += __shfl_xor(v, 8, 64);
        lsum[r] = v;
    }

    __syncthreads();   // loop done; reuse rpb_s as x2 redistribute buffer
    float* x2s = reinterpret_cast<float*>(&rpb_s[0][0][0][0]);  // [16i][8h][64c]
    if (lg < 2) {
        #pragma unroll
        for (int il = 0; il < 2; ++il)
            #pragma unroll
            for (int cg = 0; cg < 4; ++cg)
                #pragma unroll
                for (int r = 0; r < 4; ++r)
                    x2s[((2 * w + il) * 8 + 4 * lg + r) * 64 + cg * 16 + l16] =
                        x2[il][cg][r];
    }
    __syncthreads();

    #pragma unroll
    for (int cs = 0; cs < 4; ++cs)
        #pragma unroll
        for (int r = 0; r < 4; ++r) {
            int ir = lg * 4 + r;
            float val = x1[cs][r] + x2s[(ir * 8 + w) * 64 + cs * 16 + l16];
            xpart[((size_t)js << 20) + ((size_t)(b * 1024 + i0 + ir)) * 512
                  + w * 64 + cs * 16 + l16] = val;
        }
    if (l16 == 0) {
        #pragma unroll
        for (int r = 0; r < 4; ++r)
            lsump[((size_t)js << 14) + (b * 8 + w) * 1024 + i0 + lg * 4 + r] = lsum[r];
    }
#undef ATTN_ITER
#undef X1_BODY
#undef X2_BODY
#undef RPB_ISSUE
#undef RPB_WRITE
#undef KH_ISSUE
#undef KH_WRITE
#undef VT_ISSUE
#undef VT_WRITE
}

// ---------------------------------------------------------------------------
extern "C" void kernel_launch(void* const* d_in, const int* in_sizes, int n_in,
                              void* d_out, int out_size, void* d_ws, size_t ws_size,
                              hipStream_t stream)
{
    (void)in_sizes; (void)n_in; (void)out_size; (void)ws_size;
    const float* q    = (const float*)d_in[0];
    const float* k    = (const float*)d_in[1];
    const float* v    = (const float*)d_in[2];
    const float* rpb  = (const float*)d_in[3];
    const float* mask = (const float*)d_in[4];
    const float* Wq   = (const float*)d_in[5];
    const float* Wk   = (const float*)d_in[6];
    const float* Wv   = (const float*)d_in[7];
    const float* Wp   = (const float*)d_in[8];
    const float* bp   = (const float*)d_in[9];
    float* out = (float*)d_out;

    unsigned short* qhb = (unsigned short*)d_ws;     // bf16 [2,8,1024,64]
    unsigned short* khb = qhb + 1048576;
    unsigned short* vtb = khb + 1048576;             // bf16 [2,8,64,1024]
    float* xpart = (float*)(vtb + 1048576);          // [2][2048][512]
    float* lsump = xpart + 2097152;                  // [2][16384]
    unsigned short* wT = (unsigned short*)(lsump + 32768); // bf16 [5][512][512]

    wprep<<<dim3(8, 8, 4), 256, 0, stream>>>(Wq, Wk, Wv, Wp, wT);

    proj_mfma<<<dim3(32, 8, 3), 256, 0, stream>>>(q, k, v, wT, qhb, khb, vtb);

    attn_mfma<<<256, 512, 0, stream>>>(qhb, khb, vtb, rpb, mask, xpart, lsump);

    out_mfma<<<dim3(32, 8), 256, 0, stream>>>(xpart, lsump, wT, bp, out);
}